// Round 1
// baseline (406.982 us; speedup 1.0000x reference)
//
#include <hip/hip_runtime.h>
#include <math.h>

#define BB 16
#define CC 512
#define HWS 4096
#define EPSV 1e-8f
#define TK 12
#define NEGINF (-3.402823466e+38f)

// workspace layout (float offsets)
#define OFF_PFG 0
#define OFF_PBG (BB*HWS)            // 65536
#define OFF_QN  (2*BB*HWS)
#define OFF_CF  (3*BB*HWS)
#define OFF_CB  (4*BB*HWS)
#define OFF_SN  (5*BB*HWS)          // supp norms: fp[16], bp[16]
#define OFF_PN  (OFF_SN + 2*BB)     // proto norms: fp[16], bp[16]
#define OFF_CNT (OFF_PN + 2*BB)     // int counts: fg[16], bg[16]
#define OFF_TKI (OFF_CNT + 2*BB)    // int topk idx: [2][16][12]
#define OFF_BMM (OFF_TKI + 2*BB*TK) // per-block minmax: 256*4
#define OFF_FMM (OFF_BMM + 256*4)   // final: {minf, 1/rangef, minb, 1/rangeb}

// ---------------- K0: support prototype norms ----------------
__global__ void k0_snorm(const float* __restrict__ sfp, const float* __restrict__ sbp,
                         float* __restrict__ snorm) {
    int b = blockIdx.x;
    int t = threadIdx.x; // 64 threads = 1 wave
    float s1 = 0.f, s2 = 0.f;
    for (int c = t; c < CC; c += 64) {
        float v = sfp[b * CC + c]; s1 += v * v;
        float w = sbp[b * CC + c]; s2 += w * w;
    }
    for (int off = 32; off; off >>= 1) {
        s1 += __shfl_down(s1, off);
        s2 += __shfl_down(s2, off);
    }
    if (t == 0) { snorm[b] = sqrtf(s1); snorm[BB + b] = sqrtf(s2); }
}

// ---------------- K1: sims vs support protos -> pred, qnorm ----------------
__global__ void k1_sim(const float* __restrict__ q, const float* __restrict__ sfp,
                       const float* __restrict__ sbp, const float* __restrict__ snorm,
                       float* __restrict__ pfg, float* __restrict__ pbg,
                       float* __restrict__ qn) {
    int b = blockIdx.y;
    int hw = blockIdx.x * 256 + threadIdx.x;
    __shared__ float sf[CC], sb[CC];
    for (int c = threadIdx.x; c < CC; c += 256) {
        sf[c] = sfp[b * CC + c];
        sb[c] = sbp[b * CC + c];
    }
    __syncthreads();
    const float* qp = q + (size_t)b * CC * HWS + hw;
    float dfg = 0.f, dbg = 0.f, qq = 0.f;
#pragma unroll 8
    for (int c = 0; c < CC; c++) {
        float v = qp[(size_t)c * HWS];
        dfg += v * sf[c];
        dbg += v * sb[c];
        qq  += v * v;
    }
    float na = sqrtf(qq);
    float den = fmaxf(na, EPSV);
    float simf = dfg / (den * fmaxf(snorm[b], EPSV));
    float simb = dbg / (den * fmaxf(snorm[BB + b], EPSV));
    // softmax over {10*simb, 10*simf} with max-subtraction (matches jax.nn.softmax)
    float a = 10.f * simb, c2 = 10.f * simf;
    float m = fmaxf(a, c2);
    float ea = expf(a - m), eb = expf(c2 - m);
    float inv = 1.f / (ea + eb);
    pfg[b * HWS + hw] = eb * inv;
    pbg[b * HWS + hw] = ea * inv;
    qn[b * HWS + hw] = na;
}

// ---------------- K2: per-b counts + top-12 (both classes) ----------------
__global__ void k2_topk(const float* __restrict__ pfg, const float* __restrict__ pbg,
                        const float* __restrict__ tau,
                        int* __restrict__ cnts, int* __restrict__ tki) {
    int b = blockIdx.x;
    int t = threadIdx.x; // 256 threads
    __shared__ float vals[HWS];
    __shared__ float rv[256];
    __shared__ int   ri[256];
    __shared__ int   s_cnt;
    float thres_fg = 1.f / (1.f + expf(-tau[0]));
    for (int cls = 0; cls < 2; cls++) {
        const float* pr = cls ? pbg : pfg;
        float thres = cls ? (1.f - thres_fg) : thres_fg;
        if (t == 0) s_cnt = 0;
        __syncthreads();
        int cnt = 0;
        for (int i = t; i < HWS; i += 256) {
            float v = pr[b * HWS + i];
            vals[i] = v;
            cnt += (v > thres) ? 1 : 0;
        }
        atomicAdd(&s_cnt, cnt);
        __syncthreads();
        if (t == 0) cnts[cls * BB + b] = s_cnt;
        for (int k = 0; k < TK; k++) {
            float bv = NEGINF; int bi = HWS;
            for (int i = t; i < HWS; i += 256) {
                float v = vals[i];
                if (v > bv) { bv = v; bi = i; } // ascending scan => lowest idx kept on ties
            }
            rv[t] = bv; ri[t] = bi;
            __syncthreads();
            for (int s = 128; s; s >>= 1) {
                if (t < s) {
                    float ov = rv[t + s]; int oi = ri[t + s];
                    if (ov > rv[t] || (ov == rv[t] && oi < ri[t])) { rv[t] = ov; ri[t] = oi; }
                }
                __syncthreads();
            }
            if (t == 0) {
                tki[(cls * BB + b) * TK + k] = ri[0];
                vals[ri[0]] = NEGINF;
            }
            __syncthreads();
        }
        __syncthreads();
    }
}

// ---------------- K3: masked channel sums -> prototypes ----------------
#define CHUNK 32
__global__ void k3_proto(const float* __restrict__ q, const float* __restrict__ pfg,
                         const float* __restrict__ pbg, const float* __restrict__ tau,
                         const int* __restrict__ cnts, const int* __restrict__ tki,
                         float* __restrict__ out_fp, float* __restrict__ out_bp) {
    int b = blockIdx.y;
    int c0 = blockIdx.x * CHUNK;
    int t = threadIdx.x; // 256
    __shared__ float mf[HWS], mb[HWS];
    float thres_fg = 1.f / (1.f + expf(-tau[0]));
    float thres_bg = 1.f - thres_fg;
    for (int i = t; i < HWS; i += 256) {
        mf[i] = (pfg[b * HWS + i] > thres_fg) ? 1.f : 0.f;
        mb[i] = (pbg[b * HWS + i] > thres_bg) ? 1.f : 0.f;
    }
    __syncthreads();
    int wave = t >> 6, lane = t & 63;
    int cntf = cnts[b], cntb = cnts[BB + b];
    const float4* mf4 = (const float4*)mf;
    const float4* mb4 = (const float4*)mb;
    for (int ci = wave; ci < CHUNK; ci += 4) {
        int c = c0 + ci;
        const float* qp = q + (size_t)b * CC * HWS + (size_t)c * HWS;
        const float4* qp4 = (const float4*)qp;
        float sfv = 0.f, sbv = 0.f;
#pragma unroll 4
        for (int j = 0; j < HWS / 256; j++) {
            int i4 = j * 64 + lane;
            float4 v = qp4[i4];
            float4 m1 = mf4[i4];
            float4 m2 = mb4[i4];
            sfv += v.x * m1.x + v.y * m1.y + v.z * m1.z + v.w * m1.w;
            sbv += v.x * m2.x + v.y * m2.y + v.z * m2.z + v.w * m2.w;
        }
        for (int off = 32; off; off >>= 1) {
            sfv += __shfl_down(sfv, off);
            sbv += __shfl_down(sbv, off);
        }
        if (lane == 0) {
            float fpv, bpv;
            if (cntf > 0) fpv = sfv / (float)cntf;
            else {
                float tf = 0.f;
                for (int j = 0; j < TK; j++) tf += qp[tki[b * TK + j]];
                fpv = tf / (float)TK;
            }
            if (cntb > 0) bpv = sbv / (float)cntb;
            else {
                float tb = 0.f;
                for (int j = 0; j < TK; j++) tb += qp[tki[(BB + b) * TK + j]];
                bpv = tb / (float)TK;
            }
            out_fp[b * CC + c] = fpv;
            out_bp[b * CC + c] = bpv;
        }
    }
}

// ---------------- K3b: query prototype norms ----------------
__global__ void k3b_pnorm(const float* __restrict__ ofp, const float* __restrict__ obp,
                          float* __restrict__ pnorm) {
    int b = blockIdx.x;
    int t = threadIdx.x; // 64
    float s1 = 0.f, s2 = 0.f;
    for (int c = t; c < CC; c += 64) {
        float v = ofp[b * CC + c]; s1 += v * v;
        float w = obp[b * CC + c]; s2 += w * w;
    }
    for (int off = 32; off; off >>= 1) {
        s1 += __shfl_down(s1, off);
        s2 += __shfl_down(s2, off);
    }
    if (t == 0) { pnorm[b] = sqrtf(s1); pnorm[BB + b] = sqrtf(s2); }
}

// ---------------- K4: cosines vs new protos + per-block minmax ----------------
__global__ void k4_cos(const float* __restrict__ q, const float* __restrict__ ofp,
                       const float* __restrict__ obp, const float* __restrict__ pnorm,
                       const float* __restrict__ qn,
                       float* __restrict__ cf, float* __restrict__ cb,
                       float* __restrict__ bmm) {
    int b = blockIdx.y;
    int hw = blockIdx.x * 256 + threadIdx.x;
    __shared__ float pf[CC], pb[CC];
    for (int c = threadIdx.x; c < CC; c += 256) {
        pf[c] = ofp[b * CC + c];
        pb[c] = obp[b * CC + c];
    }
    __syncthreads();
    const float* qp = q + (size_t)b * CC * HWS + hw;
    float df = 0.f, db = 0.f;
#pragma unroll 8
    for (int c = 0; c < CC; c++) {
        float v = qp[(size_t)c * HWS];
        df += v * pf[c];
        db += v * pb[c];
    }
    float na = fmaxf(qn[b * HWS + hw], EPSV);
    float cfv = df / (na * fmaxf(pnorm[b], EPSV));
    float cbv = db / (na * fmaxf(pnorm[BB + b], EPSV));
    cf[b * HWS + hw] = cfv;
    cb[b * HWS + hw] = cbv;
    // block minmax reduce (4 quantities)
    float mnf = cfv, mxf = cfv, mnb = cbv, mxb = cbv;
    for (int off = 32; off; off >>= 1) {
        mnf = fminf(mnf, __shfl_down(mnf, off));
        mxf = fmaxf(mxf, __shfl_down(mxf, off));
        mnb = fminf(mnb, __shfl_down(mnb, off));
        mxb = fmaxf(mxb, __shfl_down(mxb, off));
    }
    __shared__ float s4[4][4];
    int wave = threadIdx.x >> 6, lane = threadIdx.x & 63;
    if (lane == 0) { s4[wave][0] = mnf; s4[wave][1] = mxf; s4[wave][2] = mnb; s4[wave][3] = mxb; }
    __syncthreads();
    if (threadIdx.x == 0) {
        float a0 = s4[0][0], a1 = s4[0][1], a2 = s4[0][2], a3 = s4[0][3];
        for (int w = 1; w < 4; w++) {
            a0 = fminf(a0, s4[w][0]);
            a1 = fmaxf(a1, s4[w][1]);
            a2 = fminf(a2, s4[w][2]);
            a3 = fmaxf(a3, s4[w][3]);
        }
        int blk = blockIdx.y * gridDim.x + blockIdx.x;
        bmm[blk * 4 + 0] = a0;
        bmm[blk * 4 + 1] = a1;
        bmm[blk * 4 + 2] = a2;
        bmm[blk * 4 + 3] = a3;
    }
}

// ---------------- K5: global minmax ----------------
__global__ void k5_minmax(const float* __restrict__ bmm, float* __restrict__ fmm) {
    int t = threadIdx.x; // 256 threads, 256 block entries
    float mnf = bmm[t * 4 + 0], mxf = bmm[t * 4 + 1];
    float mnb = bmm[t * 4 + 2], mxb = bmm[t * 4 + 3];
    for (int off = 32; off; off >>= 1) {
        mnf = fminf(mnf, __shfl_down(mnf, off));
        mxf = fmaxf(mxf, __shfl_down(mxf, off));
        mnb = fminf(mnb, __shfl_down(mnb, off));
        mxb = fmaxf(mxb, __shfl_down(mxb, off));
    }
    __shared__ float s4[4][4];
    int wave = t >> 6, lane = t & 63;
    if (lane == 0) { s4[wave][0] = mnf; s4[wave][1] = mxf; s4[wave][2] = mnb; s4[wave][3] = mxb; }
    __syncthreads();
    if (t == 0) {
        float a0 = s4[0][0], a1 = s4[0][1], a2 = s4[0][2], a3 = s4[0][3];
        for (int w = 1; w < 4; w++) {
            a0 = fminf(a0, s4[w][0]);
            a1 = fmaxf(a1, s4[w][1]);
            a2 = fminf(a2, s4[w][2]);
            a3 = fmaxf(a3, s4[w][3]);
        }
        fmm[0] = a0;
        fmm[1] = 1.f / (a1 - a0);
        fmm[2] = a2;
        fmm[3] = 1.f / (a3 - a2);
    }
}

// ---------------- K6: final blend ----------------
__global__ void k6_out(const float* __restrict__ q, const float* __restrict__ cf,
                       const float* __restrict__ cb, const float* __restrict__ fmm,
                       float* __restrict__ out) {
    size_t idx = (size_t)blockIdx.x * 256 + threadIdx.x; // float4 index
    float minf = fmm[0], rf = fmm[1], minb = fmm[2], rb = fmm[3];
    size_t chan = idx >> 10;      // / (HWS/4)
    int h4 = (int)(idx & 1023);
    int b = (int)(chan >> 9);     // / CC
    float4 qv = ((const float4*)q)[idx];
    float4 c1 = ((const float4*)(cf + (size_t)b * HWS))[h4];
    float4 c2 = ((const float4*)(cb + (size_t)b * HWS))[h4];
    float4 o;
    o.x = qv.x * ((c1.x - minf) * rf) + qv.x * (1.f - (c2.x - minb) * rb);
    o.y = qv.y * ((c1.y - minf) * rf) + qv.y * (1.f - (c2.y - minb) * rb);
    o.z = qv.z * ((c1.z - minf) * rf) + qv.z * (1.f - (c2.z - minb) * rb);
    o.w = qv.w * ((c1.w - minf) * rf) + qv.w * (1.f - (c2.w - minb) * rb);
    ((float4*)out)[idx] = o;
}

extern "C" void kernel_launch(void* const* d_in, const int* in_sizes, int n_in,
                              void* d_out, int out_size, void* d_ws, size_t ws_size,
                              hipStream_t stream) {
    const float* sfp = (const float*)d_in[0];
    const float* sbp = (const float*)d_in[1];
    const float* q   = (const float*)d_in[2];
    const float* tau = (const float*)d_in[3];
    float* out = (float*)d_out;
    float* wsf = (float*)d_ws;

    float* pfg = wsf + OFF_PFG;
    float* pbg = wsf + OFF_PBG;
    float* qn  = wsf + OFF_QN;
    float* cf  = wsf + OFF_CF;
    float* cb  = wsf + OFF_CB;
    float* snorm = wsf + OFF_SN;
    float* pnorm = wsf + OFF_PN;
    int*   cnts  = (int*)(wsf + OFF_CNT);
    int*   tki   = (int*)(wsf + OFF_TKI);
    float* bmm   = wsf + OFF_BMM;
    float* fmm   = wsf + OFF_FMM;

    float* out_fp = out + (size_t)BB * CC * HWS;
    float* out_bp = out_fp + BB * CC;

    k0_snorm<<<BB, 64, 0, stream>>>(sfp, sbp, snorm);
    k1_sim<<<dim3(HWS / 256, BB), 256, 0, stream>>>(q, sfp, sbp, snorm, pfg, pbg, qn);
    k2_topk<<<BB, 256, 0, stream>>>(pfg, pbg, tau, cnts, tki);
    k3_proto<<<dim3(CC / CHUNK, BB), 256, 0, stream>>>(q, pfg, pbg, tau, cnts, tki, out_fp, out_bp);
    k3b_pnorm<<<BB, 64, 0, stream>>>(out_fp, out_bp, pnorm);
    k4_cos<<<dim3(HWS / 256, BB), 256, 0, stream>>>(q, out_fp, out_bp, pnorm, qn, cf, cb, bmm);
    k5_minmax<<<1, 256, 0, stream>>>(bmm, fmm);
    k6_out<<<(BB * CC * HWS / 4) / 256, 256, 0, stream>>>(q, cf, cb, fmm, out);
}

// Round 2
// 323.392 us; speedup vs baseline: 1.2585x; 1.2585x over previous
//
#include <hip/hip_runtime.h>
#include <math.h>

#define BB 16
#define CC 512
#define HWS 4096
#define EPSV 1e-8f
#define TK 12
#define NEGINF (-3.402823466e+38f)
#define CSPLIT 8
#define CCH (CC / CSPLIT)   // 64 channels per split

// workspace layout (float offsets); all float4-aligned
#define OFF_PFG 0
#define OFF_PBG (BB * HWS)
#define OFF_QN  (2 * BB * HWS)
#define OFF_CF  (3 * BB * HWS)
#define OFF_CB  (4 * BB * HWS)
#define OFF_SN  (5 * BB * HWS)        // supp norms fp[16], bp[16]
#define OFF_PN  (OFF_SN + 2 * BB)     // proto norms fp[16], bp[16]
#define OFF_CNT (OFF_PN + 2 * BB)     // int counts fg[16], bg[16]
#define OFF_TKI (OFF_CNT + 2 * BB)    // int topk idx [2][16][12] -> 384
#define OFF_BMM (OFF_TKI + 2 * BB * TK) // per-block minmax 64*4
#define OFF_FMM (OFF_BMM + 64 * 4)    // {minf, 1/rangef, minb, 1/rangeb}
#define OFF_PD1 (OFF_FMM + 4)                     // partial df: CSPLIT*BB*HWS
#define OFF_PD2 (OFF_PD1 + CSPLIT * BB * HWS)     // partial db
#define OFF_PQQ (OFF_PD2 + CSPLIT * BB * HWS)     // partial qq (k1 only; k4 reuses PD1/PD2)

__device__ __forceinline__ float sigmoidf_(float x) { return 1.f / (1.f + expf(-x)); }

// ---------------- K0: support prototype norms ----------------
__global__ void k0_snorm(const float* __restrict__ sfp, const float* __restrict__ sbp,
                         float* __restrict__ snorm) {
    int b = blockIdx.x;
    int t = threadIdx.x; // 64 = 1 wave
    float s1 = 0.f, s2 = 0.f;
    for (int c = t; c < CC; c += 64) {
        float v = sfp[b * CC + c]; s1 += v * v;
        float w = sbp[b * CC + c]; s2 += w * w;
    }
    for (int off = 32; off; off >>= 1) {
        s1 += __shfl_down(s1, off);
        s2 += __shfl_down(s2, off);
    }
    if (t == 0) { snorm[b] = sqrtf(s1); snorm[BB + b] = sqrtf(s2); }
}

// ---------------- KZ: zero the count slots ----------------
__global__ void kz_zero(int* __restrict__ cnts) {
    if (threadIdx.x < 2 * BB) cnts[threadIdx.x] = 0;
}

// ---------------- K1: split-K partial dots vs support protos ----------------
__global__ void k1_dots(const float* __restrict__ q, const float* __restrict__ sfp,
                        const float* __restrict__ sbp,
                        float* __restrict__ p_df, float* __restrict__ p_db,
                        float* __restrict__ p_qq) {
    int b = blockIdx.z, cs = blockIdx.y;
    int hw4 = blockIdx.x * 256 + threadIdx.x; // float4 index 0..1023
    __shared__ float sf[CCH], sb[CCH];
    if (threadIdx.x < CCH) sf[threadIdx.x] = sfp[b * CC + cs * CCH + threadIdx.x];
    else if (threadIdx.x < 2 * CCH) sb[threadIdx.x - CCH] = sbp[b * CC + cs * CCH + (threadIdx.x - CCH)];
    __syncthreads();
    const float4* qp4 = (const float4*)(q + (size_t)b * CC * HWS + (size_t)cs * CCH * HWS) + hw4;
    float4 df = {0, 0, 0, 0}, db = {0, 0, 0, 0}, qq = {0, 0, 0, 0};
#pragma unroll 8
    for (int j = 0; j < CCH; j++) {
        float4 v = qp4[(size_t)j * (HWS / 4)];
        float a = sf[j], c = sb[j];
        df.x += v.x * a; df.y += v.y * a; df.z += v.z * a; df.w += v.w * a;
        db.x += v.x * c; db.y += v.y * c; db.z += v.z * c; db.w += v.w * c;
        qq.x += v.x * v.x; qq.y += v.y * v.y; qq.z += v.z * v.z; qq.w += v.w * v.w;
    }
    size_t o = (size_t)(cs * BB + b) * (HWS / 4) + hw4;
    ((float4*)p_df)[o] = df;
    ((float4*)p_db)[o] = db;
    ((float4*)p_qq)[o] = qq;
}

// ---------------- K1b: combine partials -> pred, qnorm, counts ----------------
__global__ void k1b_comb(const float* __restrict__ p_df, const float* __restrict__ p_db,
                         const float* __restrict__ p_qq, const float* __restrict__ snorm,
                         const float* __restrict__ tau,
                         float* __restrict__ pfg, float* __restrict__ pbg,
                         float* __restrict__ qn, int* __restrict__ cnts) {
    int b = blockIdx.y;
    int hw4 = blockIdx.x * 256 + threadIdx.x; // 0..1023
    float4 df = {0, 0, 0, 0}, db = {0, 0, 0, 0}, qq = {0, 0, 0, 0};
    for (int cs = 0; cs < CSPLIT; cs++) {
        size_t o = (size_t)(cs * BB + b) * (HWS / 4) + hw4;
        float4 a = ((const float4*)p_df)[o];
        float4 c = ((const float4*)p_db)[o];
        float4 e = ((const float4*)p_qq)[o];
        df.x += a.x; df.y += a.y; df.z += a.z; df.w += a.w;
        db.x += c.x; db.y += c.y; db.z += c.z; db.w += c.w;
        qq.x += e.x; qq.y += e.y; qq.z += e.z; qq.w += e.w;
    }
    float snf = fmaxf(snorm[b], EPSV), snb = fmaxf(snorm[BB + b], EPSV);
    float thres_fg = sigmoidf_(tau[0]);
    float thres_bg = 1.f - thres_fg;
    float4 opf, opb, oqn;
    int cfg = 0, cbg = 0;
    float dfa[4] = {df.x, df.y, df.z, df.w};
    float dba[4] = {db.x, db.y, db.z, db.w};
    float qqa[4] = {qq.x, qq.y, qq.z, qq.w};
    float pfa[4], pba[4], qna[4];
#pragma unroll
    for (int i = 0; i < 4; i++) {
        float na = sqrtf(qqa[i]);
        float den = fmaxf(na, EPSV);
        float simf = dfa[i] / (den * snf);
        float simb = dba[i] / (den * snb);
        float a = 10.f * simb, c2 = 10.f * simf;
        float m = fmaxf(a, c2);
        float ea = expf(a - m), eb = expf(c2 - m);
        float inv = 1.f / (ea + eb);
        pfa[i] = eb * inv;
        pba[i] = ea * inv;
        qna[i] = na;
        cfg += (pfa[i] > thres_fg) ? 1 : 0;
        cbg += (pba[i] > thres_bg) ? 1 : 0;
    }
    opf = {pfa[0], pfa[1], pfa[2], pfa[3]};
    opb = {pba[0], pba[1], pba[2], pba[3]};
    oqn = {qna[0], qna[1], qna[2], qna[3]};
    size_t o = (size_t)b * (HWS / 4) + hw4;
    ((float4*)pfg)[o] = opf;
    ((float4*)pbg)[o] = opb;
    ((float4*)qn)[o] = oqn;
    // wave-level count reduce, one atomic per wave per class
    for (int off = 32; off; off >>= 1) {
        cfg += __shfl_down(cfg, off);
        cbg += __shfl_down(cbg, off);
    }
    if ((threadIdx.x & 63) == 0) {
        atomicAdd(&cnts[b], cfg);
        atomicAdd(&cnts[BB + b], cbg);
    }
}

// ---------------- K2: top-12 fallback, only when cnt==0 ----------------
__global__ void k2_topk(const float* __restrict__ pfg, const float* __restrict__ pbg,
                        const int* __restrict__ cnts, int* __restrict__ tki) {
    int id = blockIdx.x;      // 0..31
    int cls = id >> 4, b = id & 15;
    if (cnts[cls * BB + b] > 0) return; // fallback unused -> exact skip
    int t = threadIdx.x; // 256
    __shared__ float vals[HWS];
    __shared__ float rv[256];
    __shared__ int   ri[256];
    const float* pr = cls ? pbg : pfg;
    for (int i = t; i < HWS; i += 256) vals[i] = pr[b * HWS + i];
    __syncthreads();
    for (int k = 0; k < TK; k++) {
        float bv = NEGINF; int bi = HWS;
        for (int i = t; i < HWS; i += 256) {
            float v = vals[i];
            if (v > bv) { bv = v; bi = i; }
        }
        rv[t] = bv; ri[t] = bi;
        __syncthreads();
        for (int s = 128; s; s >>= 1) {
            if (t < s) {
                float ov = rv[t + s]; int oi = ri[t + s];
                if (ov > rv[t] || (ov == rv[t] && oi < ri[t])) { rv[t] = ov; ri[t] = oi; }
            }
            __syncthreads();
        }
        if (t == 0) {
            tki[(cls * BB + b) * TK + k] = ri[0];
            vals[ri[0]] = NEGINF;
        }
        __syncthreads();
    }
}

// ---------------- K3: masked channel sums -> prototypes (1 wave/channel) ----------------
__global__ void k3_proto(const float* __restrict__ q, const float* __restrict__ pfg,
                         const float* __restrict__ pbg, const float* __restrict__ tau,
                         const int* __restrict__ cnts, const int* __restrict__ tki,
                         float* __restrict__ out_fp, float* __restrict__ out_bp) {
    int b = blockIdx.y;
    int wave = threadIdx.x >> 6, lane = threadIdx.x & 63;
    int c = blockIdx.x * 4 + wave;
    float thres_fg = sigmoidf_(tau[0]);
    float thres_bg = 1.f - thres_fg;
    const float* qp = q + (size_t)b * CC * HWS + (size_t)c * HWS;
    const float4* qp4 = (const float4*)qp;
    const float4* pf4 = (const float4*)(pfg + (size_t)b * HWS);
    const float4* pb4 = (const float4*)(pbg + (size_t)b * HWS);
    float sfv = 0.f, sbv = 0.f;
#pragma unroll 4
    for (int j = 0; j < HWS / 256; j++) {
        int i4 = j * 64 + lane;
        float4 v = qp4[i4];
        float4 m1 = pf4[i4];
        float4 m2 = pb4[i4];
        sfv += (m1.x > thres_fg ? v.x : 0.f) + (m1.y > thres_fg ? v.y : 0.f)
             + (m1.z > thres_fg ? v.z : 0.f) + (m1.w > thres_fg ? v.w : 0.f);
        sbv += (m2.x > thres_bg ? v.x : 0.f) + (m2.y > thres_bg ? v.y : 0.f)
             + (m2.z > thres_bg ? v.z : 0.f) + (m2.w > thres_bg ? v.w : 0.f);
    }
    for (int off = 32; off; off >>= 1) {
        sfv += __shfl_down(sfv, off);
        sbv += __shfl_down(sbv, off);
    }
    if (lane == 0) {
        int cntf = cnts[b], cntb = cnts[BB + b];
        float fpv, bpv;
        if (cntf > 0) fpv = sfv / (float)cntf;
        else {
            float tf = 0.f;
            for (int j = 0; j < TK; j++) tf += qp[tki[b * TK + j]];
            fpv = tf / (float)TK;
        }
        if (cntb > 0) bpv = sbv / (float)cntb;
        else {
            float tb = 0.f;
            for (int j = 0; j < TK; j++) tb += qp[tki[(BB + b) * TK + j]];
            bpv = tb / (float)TK;
        }
        out_fp[b * CC + c] = fpv;
        out_bp[b * CC + c] = bpv;
    }
}

// ---------------- K3b: query prototype norms ----------------
__global__ void k3b_pnorm(const float* __restrict__ ofp, const float* __restrict__ obp,
                          float* __restrict__ pnorm) {
    int b = blockIdx.x;
    int t = threadIdx.x; // 64
    float s1 = 0.f, s2 = 0.f;
    for (int c = t; c < CC; c += 64) {
        float v = ofp[b * CC + c]; s1 += v * v;
        float w = obp[b * CC + c]; s2 += w * w;
    }
    for (int off = 32; off; off >>= 1) {
        s1 += __shfl_down(s1, off);
        s2 += __shfl_down(s2, off);
    }
    if (t == 0) { pnorm[b] = sqrtf(s1); pnorm[BB + b] = sqrtf(s2); }
}

// ---------------- K4: split-K partial dots vs query protos ----------------
__global__ void k4_dots(const float* __restrict__ q, const float* __restrict__ ofp,
                        const float* __restrict__ obp,
                        float* __restrict__ p_df, float* __restrict__ p_db) {
    int b = blockIdx.z, cs = blockIdx.y;
    int hw4 = blockIdx.x * 256 + threadIdx.x;
    __shared__ float pf[CCH], pb[CCH];
    if (threadIdx.x < CCH) pf[threadIdx.x] = ofp[b * CC + cs * CCH + threadIdx.x];
    else if (threadIdx.x < 2 * CCH) pb[threadIdx.x - CCH] = obp[b * CC + cs * CCH + (threadIdx.x - CCH)];
    __syncthreads();
    const float4* qp4 = (const float4*)(q + (size_t)b * CC * HWS + (size_t)cs * CCH * HWS) + hw4;
    float4 df = {0, 0, 0, 0}, db = {0, 0, 0, 0};
#pragma unroll 8
    for (int j = 0; j < CCH; j++) {
        float4 v = qp4[(size_t)j * (HWS / 4)];
        float a = pf[j], c = pb[j];
        df.x += v.x * a; df.y += v.y * a; df.z += v.z * a; df.w += v.w * a;
        db.x += v.x * c; db.y += v.y * c; db.z += v.z * c; db.w += v.w * c;
    }
    size_t o = (size_t)(cs * BB + b) * (HWS / 4) + hw4;
    ((float4*)p_df)[o] = df;
    ((float4*)p_db)[o] = db;
}

// ---------------- K4b: combine -> cosines + per-block minmax ----------------
__global__ void k4b_comb(const float* __restrict__ p_df, const float* __restrict__ p_db,
                         const float* __restrict__ pnorm, const float* __restrict__ qn,
                         float* __restrict__ cf, float* __restrict__ cb,
                         float* __restrict__ bmm) {
    int b = blockIdx.y;
    int hw4 = blockIdx.x * 256 + threadIdx.x;
    float4 df = {0, 0, 0, 0}, db = {0, 0, 0, 0};
    for (int cs = 0; cs < CSPLIT; cs++) {
        size_t o = (size_t)(cs * BB + b) * (HWS / 4) + hw4;
        float4 a = ((const float4*)p_df)[o];
        float4 c = ((const float4*)p_db)[o];
        df.x += a.x; df.y += a.y; df.z += a.z; df.w += a.w;
        db.x += c.x; db.y += c.y; db.z += c.z; db.w += c.w;
    }
    size_t o = (size_t)b * (HWS / 4) + hw4;
    float4 nv = ((const float4*)qn)[o];
    float pnf = fmaxf(pnorm[b], EPSV), pnb = fmaxf(pnorm[BB + b], EPSV);
    float dfa[4] = {df.x, df.y, df.z, df.w};
    float dba[4] = {db.x, db.y, db.z, db.w};
    float nva[4] = {nv.x, nv.y, nv.z, nv.w};
    float cfa[4], cba[4];
    float mnf = 1e38f, mxf = -1e38f, mnb = 1e38f, mxb = -1e38f;
#pragma unroll
    for (int i = 0; i < 4; i++) {
        float na = fmaxf(nva[i], EPSV);
        cfa[i] = dfa[i] / (na * pnf);
        cba[i] = dba[i] / (na * pnb);
        mnf = fminf(mnf, cfa[i]); mxf = fmaxf(mxf, cfa[i]);
        mnb = fminf(mnb, cba[i]); mxb = fmaxf(mxb, cba[i]);
    }
    float4 ocf = {cfa[0], cfa[1], cfa[2], cfa[3]};
    float4 ocb = {cba[0], cba[1], cba[2], cba[3]};
    ((float4*)cf)[o] = ocf;
    ((float4*)cb)[o] = ocb;
    for (int off = 32; off; off >>= 1) {
        mnf = fminf(mnf, __shfl_down(mnf, off));
        mxf = fmaxf(mxf, __shfl_down(mxf, off));
        mnb = fminf(mnb, __shfl_down(mnb, off));
        mxb = fmaxf(mxb, __shfl_down(mxb, off));
    }
    __shared__ float s4[4][4];
    int wave = threadIdx.x >> 6, lane = threadIdx.x & 63;
    if (lane == 0) { s4[wave][0] = mnf; s4[wave][1] = mxf; s4[wave][2] = mnb; s4[wave][3] = mxb; }
    __syncthreads();
    if (threadIdx.x == 0) {
        float a0 = s4[0][0], a1 = s4[0][1], a2 = s4[0][2], a3 = s4[0][3];
        for (int w = 1; w < 4; w++) {
            a0 = fminf(a0, s4[w][0]);
            a1 = fmaxf(a1, s4[w][1]);
            a2 = fminf(a2, s4[w][2]);
            a3 = fmaxf(a3, s4[w][3]);
        }
        int blk = blockIdx.y * gridDim.x + blockIdx.x; // 64 blocks
        bmm[blk * 4 + 0] = a0;
        bmm[blk * 4 + 1] = a1;
        bmm[blk * 4 + 2] = a2;
        bmm[blk * 4 + 3] = a3;
    }
}

// ---------------- K5: global minmax (64 entries, 1 wave) ----------------
__global__ void k5_minmax(const float* __restrict__ bmm, float* __restrict__ fmm) {
    int t = threadIdx.x; // 64
    float mnf = bmm[t * 4 + 0], mxf = bmm[t * 4 + 1];
    float mnb = bmm[t * 4 + 2], mxb = bmm[t * 4 + 3];
    for (int off = 32; off; off >>= 1) {
        mnf = fminf(mnf, __shfl_down(mnf, off));
        mxf = fmaxf(mxf, __shfl_down(mxf, off));
        mnb = fminf(mnb, __shfl_down(mnb, off));
        mxb = fmaxf(mxb, __shfl_down(mxb, off));
    }
    if (t == 0) {
        fmm[0] = mnf;
        fmm[1] = 1.f / (mxf - mnf);
        fmm[2] = mnb;
        fmm[3] = 1.f / (mxb - mnb);
    }
}

// ---------------- K6: final blend ----------------
__global__ void k6_out(const float* __restrict__ q, const float* __restrict__ cf,
                       const float* __restrict__ cb, const float* __restrict__ fmm,
                       float* __restrict__ out) {
    size_t idx = (size_t)blockIdx.x * 256 + threadIdx.x; // float4 index
    float minf = fmm[0], rf = fmm[1], minb = fmm[2], rb = fmm[3];
    size_t chan = idx >> 10;      // / (HWS/4)
    int h4 = (int)(idx & 1023);
    int b = (int)(chan >> 9);     // / CC
    float4 qv = ((const float4*)q)[idx];
    float4 c1 = ((const float4*)(cf + (size_t)b * HWS))[h4];
    float4 c2 = ((const float4*)(cb + (size_t)b * HWS))[h4];
    float4 o;
    o.x = qv.x * ((c1.x - minf) * rf) + qv.x * (1.f - (c2.x - minb) * rb);
    o.y = qv.y * ((c1.y - minf) * rf) + qv.y * (1.f - (c2.y - minb) * rb);
    o.z = qv.z * ((c1.z - minf) * rf) + qv.z * (1.f - (c2.z - minb) * rb);
    o.w = qv.w * ((c1.w - minf) * rf) + qv.w * (1.f - (c2.w - minb) * rb);
    ((float4*)out)[idx] = o;
}

extern "C" void kernel_launch(void* const* d_in, const int* in_sizes, int n_in,
                              void* d_out, int out_size, void* d_ws, size_t ws_size,
                              hipStream_t stream) {
    const float* sfp = (const float*)d_in[0];
    const float* sbp = (const float*)d_in[1];
    const float* q   = (const float*)d_in[2];
    const float* tau = (const float*)d_in[3];
    float* out = (float*)d_out;
    float* wsf = (float*)d_ws;

    float* pfg = wsf + OFF_PFG;
    float* pbg = wsf + OFF_PBG;
    float* qn  = wsf + OFF_QN;
    float* cf  = wsf + OFF_CF;
    float* cb  = wsf + OFF_CB;
    float* snorm = wsf + OFF_SN;
    float* pnorm = wsf + OFF_PN;
    int*   cnts  = (int*)(wsf + OFF_CNT);
    int*   tki   = (int*)(wsf + OFF_TKI);
    float* bmm   = wsf + OFF_BMM;
    float* fmm   = wsf + OFF_FMM;
    float* p_df  = wsf + OFF_PD1;
    float* p_db  = wsf + OFF_PD2;
    float* p_qq  = wsf + OFF_PQQ;

    float* out_fp = out + (size_t)BB * CC * HWS;
    float* out_bp = out_fp + BB * CC;

    k0_snorm<<<BB, 64, 0, stream>>>(sfp, sbp, snorm);
    kz_zero<<<1, 64, 0, stream>>>(cnts);
    k1_dots<<<dim3(HWS / 1024, CSPLIT, BB), 256, 0, stream>>>(q, sfp, sbp, p_df, p_db, p_qq);
    k1b_comb<<<dim3(HWS / 1024, BB), 256, 0, stream>>>(p_df, p_db, p_qq, snorm, tau, pfg, pbg, qn, cnts);
    k2_topk<<<32, 256, 0, stream>>>(pfg, pbg, cnts, tki);
    k3_proto<<<dim3(CC / 4, BB), 256, 0, stream>>>(q, pfg, pbg, tau, cnts, tki, out_fp, out_bp);
    k3b_pnorm<<<BB, 64, 0, stream>>>(out_fp, out_bp, pnorm);
    k4_dots<<<dim3(HWS / 1024, CSPLIT, BB), 256, 0, stream>>>(q, out_fp, out_bp, p_df, p_db);
    k4b_comb<<<dim3(HWS / 1024, BB), 256, 0, stream>>>(p_df, p_db, pnorm, qn, cf, cb, bmm);
    k5_minmax<<<1, 64, 0, stream>>>(bmm, fmm);
    k6_out<<<(BB * CC * HWS / 4) / 256, 256, 0, stream>>>(q, cf, cb, fmm, out);
}